// Round 8
// baseline (3945.045 us; speedup 1.0000x reference)
//
#include <hip/hip_runtime.h>
#include <math.h>

// ---------------------------------------------------------------------------
// Sender: LSTM + Gumbel straight-through decode, 32 steps.
// Round 16 (r15 bundled window+fold, regressed 3904; base r12 = 3779 us).
// r15 lesson: the window pipeline SHALLOWED r12's counted 3-ahead pipeline
// (honest vmcnt(0) with ~2500cyc cover vs r12's vmcnt(8) retiring only the
// 3-steps-old stage). The finalize fold itself was proven correct.
// r16 = r12 K-loop byte-identical + ONLY the finalize fold:
//  - gates(s) prologue (running under the prologue's 12 in-flight stage
//    loads) reduces partials(s-1) per-quad, fills s_tok2[128] in LDS, and
//    writes this block's 128x128 one-hot out-slice (NP == V == 4096 makes
//    the col-slice line up). 31 finalize dispatches + launch gaps removed;
//    one finalize after the loop emits the last token.
// Geometry: 128x128 tile, 512 thr / 8 waves (wave 32x64), BK=32, 4-deep LDS
// (128 KB), K-slot XOR swizzle, counted vmcnt 8/8/8...8,8,4,0, one barrier
// per K-step, stage-after-barrier, x4-unrolled literal buffer indices.
// f16 2-way split (3 MFMA/product); products & accumulation order identical
// to r12 (absmax 0.0 there); fold logic identical to r15 (absmax 0.0).
// ---------------------------------------------------------------------------

typedef _Float16 f16;
typedef f16 f16x8 __attribute__((ext_vector_type(8)));
typedef float f32x4 __attribute__((ext_vector_type(4)));

#define F16_MIN_NORM 6.104e-5f

__device__ __forceinline__ void split_f16(float v, f16& h, f16& l) {
  f16 h0 = (fabsf(v) < F16_MIN_NORM) ? (f16)0.0f : (f16)v;
  float r = (v - (float)h0) * 4096.0f;
  h = h0; l = (f16)r;
}

__device__ __forceinline__ float sigm(float x) { return 1.0f / (1.0f + expf(-x)); }

#define GLOAD_LDS16(gsrc, ldst)                                               \
  __builtin_amdgcn_global_load_lds(                                           \
      (const __attribute__((address_space(1))) unsigned int*)(const void*)(gsrc), \
      (__attribute__((address_space(3))) unsigned int*)(void*)(ldst), 16, 0, 0)

// --------------------------- threefry / gumbel -----------------------------

__device__ __forceinline__ unsigned tf_rotl(unsigned x, int r) {
  return (x << r) | (x >> (32 - r));
}

// JAX threefry2x32-20, key (0,42), partitionable: draw = x0_out ^ x1_out.
__device__ inline float gumbel_at(unsigned idx) {
  const unsigned ks0 = 0u;
  const unsigned ks1 = 42u;
  const unsigned ks2 = 0x1BD11BDAu ^ ks0 ^ ks1;
  unsigned x0 = 0u + ks0;
  unsigned x1 = idx + ks1;
#define TFR(rot) { x0 += x1; x1 = tf_rotl(x1, rot); x1 ^= x0; }
  TFR(13) TFR(15) TFR(26) TFR(6)
  x0 += ks1; x1 += ks2 + 1u;
  TFR(17) TFR(29) TFR(16) TFR(24)
  x0 += ks2; x1 += ks0 + 2u;
  TFR(13) TFR(15) TFR(26) TFR(6)
  x0 += ks0; x1 += ks1 + 3u;
  TFR(17) TFR(29) TFR(16) TFR(24)
  x0 += ks1; x1 += ks2 + 4u;
  TFR(13) TFR(15) TFR(26) TFR(6)
  x0 += ks2; x1 += ks0 + 5u;
#undef TFR
  const unsigned bits = x0 ^ x1;
  const float f = __uint_as_float((bits >> 9) | 0x3F800000u) - 1.0f;
  const float tiny = 1.17549435082228751e-38f;
  const float u = fmaxf(tiny, f * (1.0f - tiny) + tiny);
  return -logf(-logf(u));
}

// ------------------------- setup / pack kernels ----------------------------

__global__ void init_kernel(float* __restrict__ out, const int* __restrict__ startp,
                            int* __restrict__ tok, int Tp1, int V) {
  const int b = blockIdx.x;
  const int start = *startp;
  if (threadIdx.x == 0) tok[b] = start;
  float* orow = out + (size_t)b * Tp1 * V;
  const int tq = start >> 2;
  for (int v4 = threadIdx.x; v4 < V / 4; v4 += blockDim.x) {
    float4 v = make_float4(0.f, 0.f, 0.f, 0.f);
    if (v4 == tq) ((float*)&v)[start & 3] = 1.0f;
    ((float4*)orow)[v4] = v;
  }
}

// packed gate col p: gate q=(p>>4)&3, unit u=((p>>6)<<4)+(p&15); orig row
// n' = q*H + u. wpk[p][k] = k<E ? wih[n'][k] : whh[n'][k-E], split.
__global__ void pack_gates_kernel(const float* __restrict__ wih,
                                  const float* __restrict__ whh,
                                  f16* __restrict__ w0, f16* __restrict__ w1,
                                  int E, int H, int K) {
  const int k = blockIdx.x * blockDim.x + threadIdx.x;
  const int p = blockIdx.y;
  if (k >= K) return;
  const int n = ((p >> 4) & 3) * H + ((p >> 6) << 4) + (p & 15);
  const float v = (k < E) ? wih[(size_t)n * E + k] : whh[(size_t)n * H + (k - E)];
  f16 h, l; split_f16(v, h, l);
  w0[(size_t)p * K + k] = h;
  w1[(size_t)p * K + k] = l;
}

__global__ void pack_bias_kernel(const float* __restrict__ bih,
                                 const float* __restrict__ bhh,
                                 float* __restrict__ bi, float* __restrict__ bh, int H) {
  const int p = blockIdx.x * blockDim.x + threadIdx.x;
  const int n = ((p >> 4) & 3) * H + ((p >> 6) << 4) + (p & 15);
  bi[p] = bih[n];
  bh[p] = bhh[n];
}

__global__ void split_kernel(const float* __restrict__ in,
                             f16* __restrict__ o0, f16* __restrict__ o1, int n) {
  const int i = blockIdx.x * blockDim.x + threadIdx.x;
  if (i < n) { f16 h, l; split_f16(in[i], h, l); o0[i] = h; o1[i] = l; }
}

// ----------------------- shared K-loop building block ----------------------
// block 512 thr / 8 waves, tile 128x128, BK=32, 4-deep LDS pipeline (128 KB).
// Staging: 32 1KB chunks (A-hi 8, A-lo 8, B-hi 8, B-lo 8), 4 per wave.
// Wave (wr=wid&3, wc=wid>>2) computes rows [wr*32,+32) x cols [wc*64,+64).
// Swizzle: LDS[row][slot] holds global 16B-slot (slot ^ ((row>>1)&3)).
//   stage source slot = (lane&3) ^ ((lane>>3)&3)   (srow = lane>>2)
//   read slot         = (lane>>4) ^ ((lane>>1)&3)  (row & 15 == lane & 15)

__device__ __forceinline__ void stage_chunk(
    int chunk, int srow, int scol,
    const f16* __restrict__ a0s, const f16* __restrict__ a1s, int lda, int ka, int bm,
    const f16* __restrict__ b0s, const f16* __restrict__ b1s, int ldb, int kb, int bn,
    f16 (*ldsA0)[32], f16 (*ldsA1)[32], f16 (*ldsB0)[32], f16 (*ldsB1)[32])
{
  if (chunk < 8) {
    GLOAD_LDS16(a0s + (size_t)(bm + chunk * 16 + srow) * lda + ka + scol,
                &ldsA0[chunk * 16][0]);
  } else if (chunk < 16) {
    const int s = chunk - 8;
    GLOAD_LDS16(a1s + (size_t)(bm + s * 16 + srow) * lda + ka + scol,
                &ldsA1[s * 16][0]);
  } else if (chunk < 24) {
    const int s = chunk - 16;
    GLOAD_LDS16(b0s + (size_t)(bn + s * 16 + srow) * ldb + kb + scol,
                &ldsB0[s * 16][0]);
  } else {
    const int s = chunk - 24;
    GLOAD_LDS16(b1s + (size_t)(bn + s * 16 + srow) * ldb + kb + scol,
                &ldsB1[s * 16][0]);
  }
}

#define MFMA_DECLS                                                            \
  const int tid  = threadIdx.x;                                               \
  const int lane = tid & 63;                                                  \
  const int wid  = tid >> 6;                                                  \
  const int bm   = blockIdx.y * 128;                                          \
  const int bn   = blockIdx.x * 128;                                          \
  const int wm   = (wid & 3) * 32;                                            \
  const int wn   = (wid >> 2) * 64;                                           \
  const int fr   = lane & 15;                                                 \
  const int fk   = (((lane >> 4) ^ ((lane >> 1) & 3)) * 8);                   \
  const int srow = lane >> 2;                                                 \
  const int scol = (((lane & 3) ^ ((lane >> 3) & 3)) * 8);                    \
  f32x4 acc0[2][4], acc1[2][4];                                               \
  _Pragma("unroll") for (int i = 0; i < 2; ++i)                               \
  _Pragma("unroll") for (int j = 0; j < 4; ++j) {                             \
    acc0[i][j] = (f32x4)0.0f; acc1[i][j] = (f32x4)0.0f; }

#define MFMA_LDS_DECL                                                         \
  __shared__ f16 ldsA0[4][128][32], ldsA1[4][128][32],                        \
                 ldsB0[4][128][32], ldsB1[4][128][32];

// Issue-only staging into buffer `buf` (no barriers here).
#define MFMA_STAGE_TO(buf, a0s, a1s, lda, ka, b0s, b1s, ldb, kb)              \
  { _Pragma("unroll") for (int c = 0; c < 4; ++c)                             \
      stage_chunk(wid * 4 + c, srow, scol, (a0s), (a1s), (lda), (ka), bm,     \
                  (b0s), (b1s), (ldb), (kb), bn,                              \
                  ldsA0[(buf)], ldsA1[(buf)], ldsB0[(buf)], ldsB1[(buf)]); }

#define MFMA_COMPUTE_FROM(buf)                                                \
  {                                                                           \
    f16x8 a0[2], a1[2], b0[4], b1[4];                                         \
    _Pragma("unroll") for (int i = 0; i < 2; ++i) {                           \
      a0[i] = *(const f16x8*)&ldsA0[(buf)][wm + i * 16 + fr][fk];             \
      a1[i] = *(const f16x8*)&ldsA1[(buf)][wm + i * 16 + fr][fk];             \
    }                                                                         \
    _Pragma("unroll") for (int j = 0; j < 4; ++j) {                           \
      b0[j] = *(const f16x8*)&ldsB0[(buf)][wn + j * 16 + fr][fk];             \
      b1[j] = *(const f16x8*)&ldsB1[(buf)][wn + j * 16 + fr][fk];             \
    }                                                                         \
    _Pragma("unroll") for (int i = 0; i < 2; ++i)                             \
    _Pragma("unroll") for (int j = 0; j < 4; ++j) {                           \
      acc0[i][j] = __builtin_amdgcn_mfma_f32_16x16x32_f16(a0[i], b0[j], acc0[i][j], 0, 0, 0); \
      acc1[i][j] = __builtin_amdgcn_mfma_f32_16x16x32_f16(a0[i], b1[j], acc1[i][j], 0, 0, 0); \
      acc1[i][j] = __builtin_amdgcn_mfma_f32_16x16x32_f16(a1[i], b0[j], acc1[i][j], 0, 0, 0); \
    }                                                                         \
  }

// One pipeline iteration: counted wait for buf's loads (retire only the
// 3-steps-old stage), ONE barrier (implies all waves landed their chunks for
// this buf AND finished computing the buf that DOSTAGE overwrites), then
// stage-issue (hidden under MFMA), then the MFMA cluster.
#define PIPE_ITER(buf, DOSTAGE, VM)                                           \
  asm volatile("s_waitcnt vmcnt(" #VM ")" ::: "memory");                      \
  __builtin_amdgcn_s_barrier();                                               \
  asm volatile("" ::: "memory");                                              \
  DOSTAGE                                                                     \
  asm volatile("" ::: "memory");                                              \
  __builtin_amdgcn_s_setprio(1);                                              \
  MFMA_COMPUTE_FROM(buf)                                                      \
  __builtin_amdgcn_s_setprio(0);                                              \
  asm volatile("" ::: "memory");

// 4-deep pipeline, unrolled x4 (NT must be a multiple of 4, NT >= 8).
// STAGE_T(buf, t) must be #defined per kernel.
#define PIPE_PROLOGUE  STAGE_T(0, 0) STAGE_T(1, 1) STAGE_T(2, 2)

#define PIPE_BODY(NT)                                                         \
  {                                                                           \
    int tt = 0;                                                               \
    for (; tt + 4 < (NT); tt += 4) {                                          \
      PIPE_ITER(0, STAGE_T(3, tt + 3), 8)                                     \
      PIPE_ITER(1, STAGE_T(0, tt + 4), 8)                                     \
      PIPE_ITER(2, STAGE_T(1, tt + 5), 8)                                     \
      PIPE_ITER(3, STAGE_T(2, tt + 6), 8)                                     \
    }                                                                         \
    PIPE_ITER(0, STAGE_T(3, tt + 3), 8)                                       \
    PIPE_ITER(1, {}, 8)                                                       \
    PIPE_ITER(2, {}, 4)                                                       \
    PIPE_ITER(3, {}, 0)                                                       \
  }

#define PIPE(NT) PIPE_PROLOGUE PIPE_BODY(NT)

// ------------------- h0 GEMM: h0 = t @ aff_w^T + aff_b ---------------------
__global__ __launch_bounds__(512, 2) void h0_kernel(
    const f16* __restrict__ t0, const f16* __restrict__ t1, int F,
    const f16* __restrict__ aw0, const f16* __restrict__ aw1,
    const float* __restrict__ affb,
    f16* __restrict__ h0p, f16* __restrict__ h1p, int H,
    float* __restrict__ czero)
{
  MFMA_LDS_DECL
  MFMA_DECLS
  const int NT = F / 32;
#define STAGE_T(buf, t) MFMA_STAGE_TO(buf, t0, t1, F, (t) * 32, aw0, aw1, F, (t) * 32)
  PIPE(NT)
#undef STAGE_T
  const int q4 = (lane >> 4) * 4;
  const float s12 = 1.0f / 4096.0f;
  const int cn0 = bn + wn;
#pragma unroll
  for (int j = 0; j < 4; ++j) {
    const int col = cn0 + j * 16 + fr;
    const float bb = affb[col];
#pragma unroll
    for (int i = 0; i < 2; ++i) {
#pragma unroll
      for (int r = 0; r < 4; ++r) {
        const int row = bm + wm + i * 16 + q4 + r;
        const float v = (acc0[i][j][r] + acc1[i][j][r] * s12) + bb;
        f16 hh, hl; split_f16(v, hh, hl);
        const size_t off = (size_t)row * H + col;
        h0p[off] = hh; h1p[off] = hl;
        czero[off] = 0.0f;
      }
    }
  }
}

// ------- gih table GEMM: gih[v][p] = emb[v].wih[n(p)] + bih + bhh ----------
__global__ __launch_bounds__(512, 2) void gih_kernel(
    const f16* __restrict__ e0, const f16* __restrict__ e1, int E,
    const f16* __restrict__ w0, const f16* __restrict__ w1, int K,
    const float* __restrict__ bi, const float* __restrict__ bh,
    float* __restrict__ gih, int NP)
{
  MFMA_LDS_DECL
  MFMA_DECLS
  const int NT = E / 32;
#define STAGE_T(buf, t) MFMA_STAGE_TO(buf, e0, e1, E, (t) * 32, w0, w1, K, (t) * 32)
  PIPE(NT)
#undef STAGE_T
  const int q4 = (lane >> 4) * 4;
  const float s12 = 1.0f / 4096.0f;
  const int cn0 = bn + wn;
#pragma unroll
  for (int j = 0; j < 4; ++j) {
    const int col = cn0 + j * 16 + fr;
    const float bb = bi[col] + bh[col];
#pragma unroll
    for (int i = 0; i < 2; ++i)
#pragma unroll
      for (int r = 0; r < 4; ++r) {
        const int row = bm + wm + i * 16 + q4 + r;
        gih[(size_t)row * NP + col] = (acc0[i][j][r] + acc1[i][j][r] * s12) + bb;
      }
  }
}

// ---------------- gates GEMM + folded finalize + LSTM epilogue -------------
// Prologue (step>0): reduce partials(step-1) -> tok per row (s_tok2, LDS),
// write this block's 128x128 one-hot out-slice for position `step` (valid
// since NP == V == 4096). step==0: tok from tokb. Runs under the prologue's
// 12 in-flight stage loads.
// GEMM: gates = h @ w_hh^T (K=H) + gih[tok[row]] (emb term + both biases).
__global__ __launch_bounds__(512, 2) void gates_kernel(
    const f16* __restrict__ hin0, const f16* __restrict__ hin1, int H,
    const f16* __restrict__ w0, const f16* __restrict__ w1, int K, int E,
    const float* __restrict__ gih, int NP, const int* __restrict__ tokb,
    const float* __restrict__ partM, const int* __restrict__ partI,
    float* __restrict__ out, int step, int Tp1, int V,
    float* __restrict__ cbuf,
    f16* __restrict__ hout0, f16* __restrict__ hout1)
{
  MFMA_LDS_DECL
  __shared__ int s_tok2[128];
  MFMA_DECLS
  const int NT = H / 32;
#define STAGE_T(buf, t) MFMA_STAGE_TO(buf, hin0, hin1, H, (t) * 32, w0, w1, K, E + (t) * 32)
  PIPE_PROLOGUE
  // ---- folded finalize(step-1), runs under the prologue stage loads ----
  if (step == 0) {
    for (int r = tid; r < 128; r += 512) s_tok2[r] = tokb[bm + r];
  } else {
    const int rloc = wid * 16 + (lane >> 2);        // 8 waves x 16 rows
    const int row = bm + rloc;
    const int g0 = (lane & 3) * 16;                  // 4 lanes x 16 groups
    float mx = -INFINITY; int ix = 0;
#pragma unroll
    for (int g = 0; g < 16; ++g) {
      const float om = partM[(size_t)row * 64 + g0 + g];
      const int oi = partI[(size_t)row * 64 + g0 + g];
      if (om > mx || (om == mx && oi < ix)) { mx = om; ix = oi; }
    }
#pragma unroll
    for (int m = 1; m < 4; m <<= 1) {                // quad butterfly
      const float om = __shfl_xor(mx, m, 64);
      const int oi = __shfl_xor(ix, m, 64);
      if (om > mx || (om == mx && oi < ix)) { mx = om; ix = oi; }
    }
    if ((lane & 3) == 0) s_tok2[rloc] = ix;
    // one-hot out slice: row `row`, cols [bn, bn+128), exact 1.0
    float* orow = out + ((size_t)row * Tp1 + step) * V + bn;
    const int tl = ix - bn;                          // tok local col (may be OOR)
    const int tq = tl >> 2;
#pragma unroll
    for (int k = 0; k < 8; ++k) {
      const int c4 = (lane & 3) * 8 + k;
      float4 v = make_float4(0.f, 0.f, 0.f, 0.f);
      if ((unsigned)tl < 128u && c4 == tq) ((float*)&v)[tl & 3] = 1.0f;
      ((float4*)orow)[c4] = v;
    }
  }
  // s_tok2 visibility: the first PIPE_ITER barrier precedes all epilogue
  // reads (every wave's fold-write happens before its first barrier).
  PIPE_BODY(NT)
#undef STAGE_T
  // epilogue: packed cols -> unit u = (cn0>>2)+fr, gate q = j.
  const int q4 = (lane >> 4) * 4;
  const float s12 = 1.0f / 4096.0f;
  const int cn0 = bn + wn;
  const int nunit = (cn0 >> 2) + fr;
#pragma unroll
  for (int i = 0; i < 2; ++i) {
#pragma unroll
    for (int r = 0; r < 4; ++r) {
      const int rl = wm + i * 16 + q4 + r;
      const int row = bm + rl;
      const float* gr = gih + (size_t)s_tok2[rl] * NP + cn0 + fr;
      float gv[4];
#pragma unroll
      for (int j = 0; j < 4; ++j)
        gv[j] = (acc0[i][j][r] + acc1[i][j][r] * s12) + gr[j * 16];
      const size_t off = (size_t)row * H + nunit;
      const float c = cbuf[off];
      const float cn = __fadd_rn(__fmul_rn(sigm(gv[1]), c),
                                 __fmul_rn(sigm(gv[0]), tanhf(gv[2])));
      const float hn = __fmul_rn(sigm(gv[3]), tanhf(cn));
      cbuf[off] = cn;
      f16 hh, hl; split_f16(hn, hh, hl);
      hout0[off] = hh; hout1[off] = hl;
    }
  }
}

// ------------- logits GEMM + fused argmax-partials epilogue ----------------
__global__ __launch_bounds__(512, 2) void logits_kernel(
    const f16* __restrict__ h0p, const f16* __restrict__ h1p, int H,
    const f16* __restrict__ w0, const f16* __restrict__ w1,
    const float* __restrict__ lpb,
    float* __restrict__ partM, int* __restrict__ partI,
    int step, int B, int V)
{
  MFMA_LDS_DECL
  MFMA_DECLS
  const int NT = H / 32;
#define STAGE_T(buf, t) MFMA_STAGE_TO(buf, h0p, h1p, H, (t) * 32, w0, w1, H, (t) * 32)
  PIPE(NT)
#undef STAGE_T
  const int q4 = (lane >> 4) * 4;
  const float s12 = 1.0f / 4096.0f;
  const int cn0 = bn + wn;
  float bv[4];
#pragma unroll
  for (int j = 0; j < 4; ++j) bv[j] = lpb[cn0 + j * 16 + fr];
  // w = logit + gumbel, overwrite acc0
#pragma unroll
  for (int i = 0; i < 2; ++i)
#pragma unroll
    for (int j = 0; j < 4; ++j) {
      const int col = cn0 + j * 16 + fr;
#pragma unroll
      for (int r = 0; r < 4; ++r) {
        const int row = bm + wm + i * 16 + q4 + r;
        const float logit = (acc0[i][j][r] + acc1[i][j][r] * s12) + bv[j];
        const unsigned gidx = ((unsigned)(step * B + row)) * (unsigned)V + (unsigned)col;
        acc0[i][j][r] = logit + gumbel_at(gidx);
      }
    }
  // per-row argmax over this wave's 64 cols (within each 16-lane group).
  // sc == 1.0 exactly, so no denominator partials needed.
  const int grp = cn0 >> 6;   // 64 col-groups of 64
#pragma unroll
  for (int i = 0; i < 2; ++i) {
#pragma unroll
    for (int r = 0; r < 4; ++r) {
      float mx = -INFINITY; int ix = 0;
#pragma unroll
      for (int j = 0; j < 4; ++j) {
        const float w = acc0[i][j][r];
        const int col = cn0 + j * 16 + fr;
        if (w > mx) { mx = w; ix = col; }
      }
#pragma unroll
      for (int m = 1; m < 16; m <<= 1) {
        const float om = __shfl_xor(mx, m, 64);
        const int oi = __shfl_xor(ix, m, 64);
        if (om > mx || (om == mx && oi < ix)) { mx = om; ix = oi; }
      }
      if (fr == 0) {
        const int row = bm + wm + i * 16 + q4 + r;
        partM[(size_t)row * 64 + grp] = mx;
        partI[(size_t)row * 64 + grp] = ix;
      }
    }
  }
}

// ----------- finalize: argmax reduce, write one-hot, publish tok -----------
// (used once, after the loop, for the last emitted token)
__global__ __launch_bounds__(256) void finalize_kernel(
    const float* __restrict__ partM, const int* __restrict__ partI,
    float* __restrict__ out, int* __restrict__ tok,
    int step, int Tp1, int V)
{
  const int b = blockIdx.x;
  const int tid = threadIdx.x;
  __shared__ int s_tok;

  if (tid < 64) {
    float mx = partM[(size_t)b * 64 + tid];
    int ix = partI[(size_t)b * 64 + tid];
#pragma unroll
    for (int m = 1; m < 64; m <<= 1) {
      const float om = __shfl_xor(mx, m, 64);
      const int oi = __shfl_xor(ix, m, 64);
      if (om > mx || (om == mx && oi < ix)) { mx = om; ix = oi; }
    }
    if (tid == 0) { s_tok = ix; tok[b] = ix; }
  }
  __syncthreads();
  const int tk = s_tok;

  // one-hot write with exact 1.0 (sc == (1-y)+y == 1.0f identically)
  float* orow = out + ((size_t)b * Tp1 + step + 1) * V;
  const int tq = tk >> 2;
#pragma unroll
  for (int j = 0; j < 4; ++j) {
    const int idx = tid + 256 * j;
    float4 v = make_float4(0.f, 0.f, 0.f, 0.f);
    if (idx == tq) ((float*)&v)[tk & 3] = 1.0f;
    ((float4*)orow)[idx] = v;
  }
}

// ------------------------------- host side ---------------------------------

extern "C" void kernel_launch(void* const* d_in, const int* in_sizes, int n_in,
                              void* d_out, int out_size, void* d_ws, size_t ws_size,
                              hipStream_t stream) {
  const float* t     = (const float*)d_in[0];
  const float* emb   = (const float*)d_in[1];
  const float* affw  = (const float*)d_in[2];
  const float* affb  = (const float*)d_in[3];
  const float* wih   = (const float*)d_in[4];
  const float* whh   = (const float*)d_in[5];
  const float* bih   = (const float*)d_in[6];
  const float* bhh   = (const float*)d_in[7];
  const float* lpw   = (const float*)d_in[8];
  const float* lpb   = (const float*)d_in[9];
  const int*   start = (const int*)d_in[10];
  float* out = (float*)d_out;

  const int H = in_sizes[3];             // 1024
  const int V = in_sizes[9];             // 4096
  const int E = in_sizes[1] / V;         // 256
  const int F = in_sizes[2] / H;         // 2048
  const int B = in_sizes[0] / F;         // 1024
  const int Tp1 = out_size / (B * V);    // 33
  const int T = Tp1 - 1;                 // 32
  const int KG = E + H;                  // 1280
  const int NP = 4 * H;                  // 4096 packed gate cols (== V)

  // ---- workspace layout (~190 MB) ----
  char* p = (char*)d_ws;
  float* gihb  = (float*)p; p += (size_t)V * NP * 4;          // 64 MB gih table
  float* cbuf  = (float*)p; p += (size_t)B * H * 4;           // 4 MB
  f16* hA0[2]; f16* hA1[2];
  hA0[0] = (f16*)p; p += (size_t)B * H * 2;
  hA1[0] = (f16*)p; p += (size_t)B * H * 2;
  hA0[1] = (f16*)p; p += (size_t)B * H * 2;
  hA1[1] = (f16*)p; p += (size_t)B * H * 2;                   // 8 MB
  f16* wg0 = (f16*)p; p += (size_t)V * KG * 2;                // 21 MB packed gates
  f16* wg1 = (f16*)p; p += (size_t)V * KG * 2;
  f16* wl0 = (f16*)p; p += (size_t)V * H * 2;                 // 16 MB lp_w
  f16* wl1 = (f16*)p; p += (size_t)V * H * 2;
  f16* t0  = (f16*)p; p += (size_t)B * F * 2;                 // 8 MB t planes
  f16* t1  = (f16*)p; p += (size_t)B * F * 2;
  f16* aw0 = (f16*)p; p += (size_t)H * F * 2;                 // 8 MB aff_w planes
  f16* aw1 = (f16*)p; p += (size_t)H * F * 2;
  f16* em0 = (f16*)p; p += (size_t)V * E * 2;                 // 4 MB emb planes
  f16* em1 = (f16*)p; p += (size_t)V * E * 2;
  float* bgi = (float*)p; p += (size_t)NP * 4;
  float* bgh = (float*)p; p += (size_t)NP * 4;
  float* partM = (float*)p; p += (size_t)B * 64 * 4;
  int*   partI = (int*)p;   p += (size_t)B * 64 * 4;
  int*   tokb  = (int*)p;   p += (size_t)B * 4;
  (void)ws_size; (void)n_in;

  // ---- setup ----
  init_kernel<<<B, 256, 0, stream>>>(out, start, tokb, Tp1, V);
  pack_gates_kernel<<<dim3((KG + 255) / 256, NP), 256, 0, stream>>>(
      wih, whh, wg0, wg1, E, H, KG);
  pack_bias_kernel<<<NP / 256, 256, 0, stream>>>(bih, bhh, bgi, bgh, H);
  split_kernel<<<(V * H + 255) / 256, 256, 0, stream>>>(lpw, wl0, wl1, V * H);
  split_kernel<<<(B * F + 255) / 256, 256, 0, stream>>>(t, t0, t1, B * F);
  split_kernel<<<(H * F + 255) / 256, 256, 0, stream>>>(affw, aw0, aw1, H * F);
  split_kernel<<<(V * E + 255) / 256, 256, 0, stream>>>(emb, em0, em1, V * E);
  // h0 = t @ aff_w^T + aff_b -> split into hA[0]; zero cbuf
  h0_kernel<<<dim3(H / 128, B / 128), 512, 0, stream>>>(
      t0, t1, F, aw0, aw1, affb, hA0[0], hA1[0], H, cbuf);
  // gih = emb @ w_ih^T + b_ih + b_hh (packed cols), f32
  gih_kernel<<<dim3(NP / 128, V / 128), 512, 0, stream>>>(
      em0, em1, E, wg0, wg1, KG, bgi, bgh, gihb, NP);

  for (int s = 0; s < T; ++s) {
    const int cur = s & 1, nxt = (s + 1) & 1;
    gates_kernel<<<dim3(NP / 128, B / 128), 512, 0, stream>>>(
        hA0[cur], hA1[cur], H, wg0, wg1, KG, E, gihb, NP, tokb,
        partM, partI, out, s, Tp1, V,
        cbuf, hA0[nxt], hA1[nxt]);
    logits_kernel<<<dim3(V / 128, B / 128), 512, 0, stream>>>(
        hA0[nxt], hA1[nxt], H, wl0, wl1, lpb,
        partM, partI, s, B, V);
  }
  finalize_kernel<<<B, 256, 0, stream>>>(
      partM, partI, out, tokb, T - 1, Tp1, V);
}

// Round 9
// 3922.784 us; speedup vs baseline: 1.0057x; 1.0057x over previous
//
#include <hip/hip_runtime.h>
#include <math.h>

// ---------------------------------------------------------------------------
// Sender: LSTM + Gumbel straight-through decode, 32 steps.
// Round 17 (r16 = fold-in-gates regressed 3945 vs r12 3779).
// r16 lesson: global STORES count in vmcnt. The fold's 8 stores + 32 loads
// per lane sat between the prologue's 12 stage loads and the first
// vmcnt(8) wait -> every gates launch drained the whole pipeline (~350 us
// total), swamping the ~190 us dispatch saving.
// r17 fix: fold runs BEFORE the prologue and ends with an explicit
// "s_waitcnt vmcnt(0) lgkmcnt(0)" drain. The prologue's 12 stage loads are
// then the ONLY outstanding VMEM ops -> counted waits 8/8/../8,4,0 exact
// again. Fold latency (~1 us/launch, L2-resident partials) is exposed
// serially; also makes s_tok2 LDS visibility airtight pre-barrier.
// Everything else byte-identical to r16 (GEMM core byte-identical to r12:
// 128x128 tile, 512thr/8 waves, BK=32, 4-deep LDS, K-slot XOR swizzle,
// counted vmcnt, one barrier/K-step, x4-unrolled literal buffers, f16
// 2-way split 3-MFMA/product; absmax 0.0 across r12/r15/r16).
// ---------------------------------------------------------------------------

typedef _Float16 f16;
typedef f16 f16x8 __attribute__((ext_vector_type(8)));
typedef float f32x4 __attribute__((ext_vector_type(4)));

#define F16_MIN_NORM 6.104e-5f

__device__ __forceinline__ void split_f16(float v, f16& h, f16& l) {
  f16 h0 = (fabsf(v) < F16_MIN_NORM) ? (f16)0.0f : (f16)v;
  float r = (v - (float)h0) * 4096.0f;
  h = h0; l = (f16)r;
}

__device__ __forceinline__ float sigm(float x) { return 1.0f / (1.0f + expf(-x)); }

#define GLOAD_LDS16(gsrc, ldst)                                               \
  __builtin_amdgcn_global_load_lds(                                           \
      (const __attribute__((address_space(1))) unsigned int*)(const void*)(gsrc), \
      (__attribute__((address_space(3))) unsigned int*)(void*)(ldst), 16, 0, 0)

// --------------------------- threefry / gumbel -----------------------------

__device__ __forceinline__ unsigned tf_rotl(unsigned x, int r) {
  return (x << r) | (x >> (32 - r));
}

// JAX threefry2x32-20, key (0,42), partitionable: draw = x0_out ^ x1_out.
__device__ inline float gumbel_at(unsigned idx) {
  const unsigned ks0 = 0u;
  const unsigned ks1 = 42u;
  const unsigned ks2 = 0x1BD11BDAu ^ ks0 ^ ks1;
  unsigned x0 = 0u + ks0;
  unsigned x1 = idx + ks1;
#define TFR(rot) { x0 += x1; x1 = tf_rotl(x1, rot); x1 ^= x0; }
  TFR(13) TFR(15) TFR(26) TFR(6)
  x0 += ks1; x1 += ks2 + 1u;
  TFR(17) TFR(29) TFR(16) TFR(24)
  x0 += ks2; x1 += ks0 + 2u;
  TFR(13) TFR(15) TFR(26) TFR(6)
  x0 += ks0; x1 += ks1 + 3u;
  TFR(17) TFR(29) TFR(16) TFR(24)
  x0 += ks1; x1 += ks2 + 4u;
  TFR(13) TFR(15) TFR(26) TFR(6)
  x0 += ks2; x1 += ks0 + 5u;
#undef TFR
  const unsigned bits = x0 ^ x1;
  const float f = __uint_as_float((bits >> 9) | 0x3F800000u) - 1.0f;
  const float tiny = 1.17549435082228751e-38f;
  const float u = fmaxf(tiny, f * (1.0f - tiny) + tiny);
  return -logf(-logf(u));
}

// ------------------------- setup / pack kernels ----------------------------

__global__ void init_kernel(float* __restrict__ out, const int* __restrict__ startp,
                            int* __restrict__ tok, int Tp1, int V) {
  const int b = blockIdx.x;
  const int start = *startp;
  if (threadIdx.x == 0) tok[b] = start;
  float* orow = out + (size_t)b * Tp1 * V;
  const int tq = start >> 2;
  for (int v4 = threadIdx.x; v4 < V / 4; v4 += blockDim.x) {
    float4 v = make_float4(0.f, 0.f, 0.f, 0.f);
    if (v4 == tq) ((float*)&v)[start & 3] = 1.0f;
    ((float4*)orow)[v4] = v;
  }
}

// packed gate col p: gate q=(p>>4)&3, unit u=((p>>6)<<4)+(p&15); orig row
// n' = q*H + u. wpk[p][k] = k<E ? wih[n'][k] : whh[n'][k-E], split.
__global__ void pack_gates_kernel(const float* __restrict__ wih,
                                  const float* __restrict__ whh,
                                  f16* __restrict__ w0, f16* __restrict__ w1,
                                  int E, int H, int K) {
  const int k = blockIdx.x * blockDim.x + threadIdx.x;
  const int p = blockIdx.y;
  if (k >= K) return;
  const int n = ((p >> 4) & 3) * H + ((p >> 6) << 4) + (p & 15);
  const float v = (k < E) ? wih[(size_t)n * E + k] : whh[(size_t)n * H + (k - E)];
  f16 h, l; split_f16(v, h, l);
  w0[(size_t)p * K + k] = h;
  w1[(size_t)p * K + k] = l;
}

__global__ void pack_bias_kernel(const float* __restrict__ bih,
                                 const float* __restrict__ bhh,
                                 float* __restrict__ bi, float* __restrict__ bh, int H) {
  const int p = blockIdx.x * blockDim.x + threadIdx.x;
  const int n = ((p >> 4) & 3) * H + ((p >> 6) << 4) + (p & 15);
  bi[p] = bih[n];
  bh[p] = bhh[n];
}

__global__ void split_kernel(const float* __restrict__ in,
                             f16* __restrict__ o0, f16* __restrict__ o1, int n) {
  const int i = blockIdx.x * blockDim.x + threadIdx.x;
  if (i < n) { f16 h, l; split_f16(in[i], h, l); o0[i] = h; o1[i] = l; }
}

// ----------------------- shared K-loop building block ----------------------
// block 512 thr / 8 waves, tile 128x128, BK=32, 4-deep LDS pipeline (128 KB).
// Staging: 32 1KB chunks (A-hi 8, A-lo 8, B-hi 8, B-lo 8), 4 per wave.
// Wave (wr=wid&3, wc=wid>>2) computes rows [wr*32,+32) x cols [wc*64,+64).
// Swizzle: LDS[row][slot] holds global 16B-slot (slot ^ ((row>>1)&3)).
//   stage source slot = (lane&3) ^ ((lane>>3)&3)   (srow = lane>>2)
//   read slot         = (lane>>4) ^ ((lane>>1)&3)  (row & 15 == lane & 15)

__device__ __forceinline__ void stage_chunk(
    int chunk, int srow, int scol,
    const f16* __restrict__ a0s, const f16* __restrict__ a1s, int lda, int ka, int bm,
    const f16* __restrict__ b0s, const f16* __restrict__ b1s, int ldb, int kb, int bn,
    f16 (*ldsA0)[32], f16 (*ldsA1)[32], f16 (*ldsB0)[32], f16 (*ldsB1)[32])
{
  if (chunk < 8) {
    GLOAD_LDS16(a0s + (size_t)(bm + chunk * 16 + srow) * lda + ka + scol,
                &ldsA0[chunk * 16][0]);
  } else if (chunk < 16) {
    const int s = chunk - 8;
    GLOAD_LDS16(a1s + (size_t)(bm + s * 16 + srow) * lda + ka + scol,
                &ldsA1[s * 16][0]);
  } else if (chunk < 24) {
    const int s = chunk - 16;
    GLOAD_LDS16(b0s + (size_t)(bn + s * 16 + srow) * ldb + kb + scol,
                &ldsB0[s * 16][0]);
  } else {
    const int s = chunk - 24;
    GLOAD_LDS16(b1s + (size_t)(bn + s * 16 + srow) * ldb + kb + scol,
                &ldsB1[s * 16][0]);
  }
}

#define MFMA_DECLS                                                            \
  const int tid  = threadIdx.x;                                               \
  const int lane = tid & 63;                                                  \
  const int wid  = tid >> 6;                                                  \
  const int bm   = blockIdx.y * 128;                                          \
  const int bn   = blockIdx.x * 128;                                          \
  const int wm   = (wid & 3) * 32;                                            \
  const int wn   = (wid >> 2) * 64;                                           \
  const int fr   = lane & 15;                                                 \
  const int fk   = (((lane >> 4) ^ ((lane >> 1) & 3)) * 8);                   \
  const int srow = lane >> 2;                                                 \
  const int scol = (((lane & 3) ^ ((lane >> 3) & 3)) * 8);                    \
  f32x4 acc0[2][4], acc1[2][4];                                               \
  _Pragma("unroll") for (int i = 0; i < 2; ++i)                               \
  _Pragma("unroll") for (int j = 0; j < 4; ++j) {                             \
    acc0[i][j] = (f32x4)0.0f; acc1[i][j] = (f32x4)0.0f; }

#define MFMA_LDS_DECL                                                         \
  __shared__ f16 ldsA0[4][128][32], ldsA1[4][128][32],                        \
                 ldsB0[4][128][32], ldsB1[4][128][32];

// Issue-only staging into buffer `buf` (no barriers here).
#define MFMA_STAGE_TO(buf, a0s, a1s, lda, ka, b0s, b1s, ldb, kb)              \
  { _Pragma("unroll") for (int c = 0; c < 4; ++c)                             \
      stage_chunk(wid * 4 + c, srow, scol, (a0s), (a1s), (lda), (ka), bm,     \
                  (b0s), (b1s), (ldb), (kb), bn,                              \
                  ldsA0[(buf)], ldsA1[(buf)], ldsB0[(buf)], ldsB1[(buf)]); }

#define MFMA_COMPUTE_FROM(buf)                                                \
  {                                                                           \
    f16x8 a0[2], a1[2], b0[4], b1[4];                                         \
    _Pragma("unroll") for (int i = 0; i < 2; ++i) {                           \
      a0[i] = *(const f16x8*)&ldsA0[(buf)][wm + i * 16 + fr][fk];             \
      a1[i] = *(const f16x8*)&ldsA1[(buf)][wm + i * 16 + fr][fk];             \
    }                                                                         \
    _Pragma("unroll") for (int j = 0; j < 4; ++j) {                           \
      b0[j] = *(const f16x8*)&ldsB0[(buf)][wn + j * 16 + fr][fk];             \
      b1[j] = *(const f16x8*)&ldsB1[(buf)][wn + j * 16 + fr][fk];             \
    }                                                                         \
    _Pragma("unroll") for (int i = 0; i < 2; ++i)                             \
    _Pragma("unroll") for (int j = 0; j < 4; ++j) {                           \
      acc0[i][j] = __builtin_amdgcn_mfma_f32_16x16x32_f16(a0[i], b0[j], acc0[i][j], 0, 0, 0); \
      acc1[i][j] = __builtin_amdgcn_mfma_f32_16x16x32_f16(a0[i], b1[j], acc1[i][j], 0, 0, 0); \
      acc1[i][j] = __builtin_amdgcn_mfma_f32_16x16x32_f16(a1[i], b0[j], acc1[i][j], 0, 0, 0); \
    }                                                                         \
  }

// One pipeline iteration: counted wait for buf's loads (retire only the
// 3-steps-old stage), ONE barrier (implies all waves landed their chunks for
// this buf AND finished computing the buf that DOSTAGE overwrites), then
// stage-issue (hidden under MFMA), then the MFMA cluster.
// VALID ONLY when stage loads are the sole outstanding VMEM ops (stores
// count in vmcnt too - r16 lesson).
#define PIPE_ITER(buf, DOSTAGE, VM)                                           \
  asm volatile("s_waitcnt vmcnt(" #VM ")" ::: "memory");                      \
  __builtin_amdgcn_s_barrier();                                               \
  asm volatile("" ::: "memory");                                              \
  DOSTAGE                                                                     \
  asm volatile("" ::: "memory");                                              \
  __builtin_amdgcn_s_setprio(1);                                              \
  MFMA_COMPUTE_FROM(buf)                                                      \
  __builtin_amdgcn_s_setprio(0);                                              \
  asm volatile("" ::: "memory");

// 4-deep pipeline, unrolled x4 (NT must be a multiple of 4, NT >= 8).
// STAGE_T(buf, t) must be #defined per kernel.
#define PIPE_PROLOGUE  STAGE_T(0, 0) STAGE_T(1, 1) STAGE_T(2, 2)

#define PIPE_BODY(NT)                                                         \
  {                                                                           \
    int tt = 0;                                                               \
    for (; tt + 4 < (NT); tt += 4) {                                          \
      PIPE_ITER(0, STAGE_T(3, tt + 3), 8)                                     \
      PIPE_ITER(1, STAGE_T(0, tt + 4), 8)                                     \
      PIPE_ITER(2, STAGE_T(1, tt + 5), 8)                                     \
      PIPE_ITER(3, STAGE_T(2, tt + 6), 8)                                     \
    }                                                                         \
    PIPE_ITER(0, STAGE_T(3, tt + 3), 8)                                       \
    PIPE_ITER(1, {}, 8)                                                       \
    PIPE_ITER(2, {}, 4)                                                       \
    PIPE_ITER(3, {}, 0)                                                       \
  }

#define PIPE(NT) PIPE_PROLOGUE PIPE_BODY(NT)

// ------------------- h0 GEMM: h0 = t @ aff_w^T + aff_b ---------------------
__global__ __launch_bounds__(512, 2) void h0_kernel(
    const f16* __restrict__ t0, const f16* __restrict__ t1, int F,
    const f16* __restrict__ aw0, const f16* __restrict__ aw1,
    const float* __restrict__ affb,
    f16* __restrict__ h0p, f16* __restrict__ h1p, int H,
    float* __restrict__ czero)
{
  MFMA_LDS_DECL
  MFMA_DECLS
  const int NT = F / 32;
#define STAGE_T(buf, t) MFMA_STAGE_TO(buf, t0, t1, F, (t) * 32, aw0, aw1, F, (t) * 32)
  PIPE(NT)
#undef STAGE_T
  const int q4 = (lane >> 4) * 4;
  const float s12 = 1.0f / 4096.0f;
  const int cn0 = bn + wn;
#pragma unroll
  for (int j = 0; j < 4; ++j) {
    const int col = cn0 + j * 16 + fr;
    const float bb = affb[col];
#pragma unroll
    for (int i = 0; i < 2; ++i) {
#pragma unroll
      for (int r = 0; r < 4; ++r) {
        const int row = bm + wm + i * 16 + q4 + r;
        const float v = (acc0[i][j][r] + acc1[i][j][r] * s12) + bb;
        f16 hh, hl; split_f16(v, hh, hl);
        const size_t off = (size_t)row * H + col;
        h0p[off] = hh; h1p[off] = hl;
        czero[off] = 0.0f;
      }
    }
  }
}

// ------- gih table GEMM: gih[v][p] = emb[v].wih[n(p)] + bih + bhh ----------
__global__ __launch_bounds__(512, 2) void gih_kernel(
    const f16* __restrict__ e0, const f16* __restrict__ e1, int E,
    const f16* __restrict__ w0, const f16* __restrict__ w1, int K,
    const float* __restrict__ bi, const float* __restrict__ bh,
    float* __restrict__ gih, int NP)
{
  MFMA_LDS_DECL
  MFMA_DECLS
  const int NT = E / 32;
#define STAGE_T(buf, t) MFMA_STAGE_TO(buf, e0, e1, E, (t) * 32, w0, w1, K, (t) * 32)
  PIPE(NT)
#undef STAGE_T
  const int q4 = (lane >> 4) * 4;
  const float s12 = 1.0f / 4096.0f;
  const int cn0 = bn + wn;
#pragma unroll
  for (int j = 0; j < 4; ++j) {
    const int col = cn0 + j * 16 + fr;
    const float bb = bi[col] + bh[col];
#pragma unroll
    for (int i = 0; i < 2; ++i)
#pragma unroll
      for (int r = 0; r < 4; ++r) {
        const int row = bm + wm + i * 16 + q4 + r;
        gih[(size_t)row * NP + col] = (acc0[i][j][r] + acc1[i][j][r] * s12) + bb;
      }
  }
}

// ---------------- gates GEMM + folded finalize + LSTM epilogue -------------
// Fold (step>0) runs FIRST: reduce partials(step-1) -> tok per row (s_tok2),
// write this block's 128x128 one-hot out-slice for position `step` (valid
// since NP == V == 4096). step==0: tok from tokb. Then an explicit
// vmcnt(0)+lgkmcnt(0) drain so the pipeline's counted vmcnt sees ONLY stage
// loads (stores count in vmcnt - r16 lesson).
// GEMM: gates = h @ w_hh^T (K=H) + gih[tok[row]] (emb term + both biases).
__global__ __launch_bounds__(512, 2) void gates_kernel(
    const f16* __restrict__ hin0, const f16* __restrict__ hin1, int H,
    const f16* __restrict__ w0, const f16* __restrict__ w1, int K, int E,
    const float* __restrict__ gih, int NP, const int* __restrict__ tokb,
    const float* __restrict__ partM, const int* __restrict__ partI,
    float* __restrict__ out, int step, int Tp1, int V,
    float* __restrict__ cbuf,
    f16* __restrict__ hout0, f16* __restrict__ hout1)
{
  MFMA_LDS_DECL
  __shared__ int s_tok2[128];
  MFMA_DECLS
  const int NT = H / 32;
  // ---- folded finalize(step-1), BEFORE any stage loads ----
  if (step == 0) {
    for (int r = tid; r < 128; r += 512) s_tok2[r] = tokb[bm + r];
  } else {
    const int rloc = wid * 16 + (lane >> 2);        // 8 waves x 16 rows
    const int row = bm + rloc;
    const int g0 = (lane & 3) * 16;                  // 4 lanes x 16 groups
    float mx = -INFINITY; int ix = 0;
#pragma unroll
    for (int g = 0; g < 16; ++g) {
      const float om = partM[(size_t)row * 64 + g0 + g];
      const int oi = partI[(size_t)row * 64 + g0 + g];
      if (om > mx || (om == mx && oi < ix)) { mx = om; ix = oi; }
    }
#pragma unroll
    for (int m = 1; m < 4; m <<= 1) {                // quad butterfly
      const float om = __shfl_xor(mx, m, 64);
      const int oi = __shfl_xor(ix, m, 64);
      if (om > mx || (om == mx && oi < ix)) { mx = om; ix = oi; }
    }
    if ((lane & 3) == 0) s_tok2[rloc] = ix;
    // one-hot out slice: row `row`, cols [bn, bn+128), exact 1.0
    float* orow = out + ((size_t)row * Tp1 + step) * V + bn;
    const int tl = ix - bn;                          // tok local col (may be OOR)
    const int tq = tl >> 2;
#pragma unroll
    for (int k = 0; k < 8; ++k) {
      const int c4 = (lane & 3) * 8 + k;
      float4 v = make_float4(0.f, 0.f, 0.f, 0.f);
      if ((unsigned)tl < 128u && c4 == tq) ((float*)&v)[tl & 3] = 1.0f;
      ((float4*)orow)[c4] = v;
    }
  }
  // Drain fold VMEM (loads AND stores) + LDS writes so the counted-vmcnt
  // pipeline accounting below is exact and s_tok2 is visible pre-barrier.
  asm volatile("s_waitcnt vmcnt(0) lgkmcnt(0)" ::: "memory");
#define STAGE_T(buf, t) MFMA_STAGE_TO(buf, hin0, hin1, H, (t) * 32, w0, w1, K, E + (t) * 32)
  PIPE_PROLOGUE
  PIPE_BODY(NT)
#undef STAGE_T
  // epilogue: packed cols -> unit u = (cn0>>2)+fr, gate q = j.
  const int q4 = (lane >> 4) * 4;
  const float s12 = 1.0f / 4096.0f;
  const int cn0 = bn + wn;
  const int nunit = (cn0 >> 2) + fr;
#pragma unroll
  for (int i = 0; i < 2; ++i) {
#pragma unroll
    for (int r = 0; r < 4; ++r) {
      const int rl = wm + i * 16 + q4 + r;
      const int row = bm + rl;
      const float* gr = gih + (size_t)s_tok2[rl] * NP + cn0 + fr;
      float gv[4];
#pragma unroll
      for (int j = 0; j < 4; ++j)
        gv[j] = (acc0[i][j][r] + acc1[i][j][r] * s12) + gr[j * 16];
      const size_t off = (size_t)row * H + nunit;
      const float c = cbuf[off];
      const float cn = __fadd_rn(__fmul_rn(sigm(gv[1]), c),
                                 __fmul_rn(sigm(gv[0]), tanhf(gv[2])));
      const float hn = __fmul_rn(sigm(gv[3]), tanhf(cn));
      cbuf[off] = cn;
      f16 hh, hl; split_f16(hn, hh, hl);
      hout0[off] = hh; hout1[off] = hl;
    }
  }
}

// ------------- logits GEMM + fused argmax-partials epilogue ----------------
__global__ __launch_bounds__(512, 2) void logits_kernel(
    const f16* __restrict__ h0p, const f16* __restrict__ h1p, int H,
    const f16* __restrict__ w0, const f16* __restrict__ w1,
    const float* __restrict__ lpb,
    float* __restrict__ partM, int* __restrict__ partI,
    int step, int B, int V)
{
  MFMA_LDS_DECL
  MFMA_DECLS
  const int NT = H / 32;
#define STAGE_T(buf, t) MFMA_STAGE_TO(buf, h0p, h1p, H, (t) * 32, w0, w1, H, (t) * 32)
  PIPE(NT)
#undef STAGE_T
  const int q4 = (lane >> 4) * 4;
  const float s12 = 1.0f / 4096.0f;
  const int cn0 = bn + wn;
  float bv[4];
#pragma unroll
  for (int j = 0; j < 4; ++j) bv[j] = lpb[cn0 + j * 16 + fr];
  // w = logit + gumbel, overwrite acc0
#pragma unroll
  for (int i = 0; i < 2; ++i)
#pragma unroll
    for (int j = 0; j < 4; ++j) {
      const int col = cn0 + j * 16 + fr;
#pragma unroll
      for (int r = 0; r < 4; ++r) {
        const int row = bm + wm + i * 16 + q4 + r;
        const float logit = (acc0[i][j][r] + acc1[i][j][r] * s12) + bv[j];
        const unsigned gidx = ((unsigned)(step * B + row)) * (unsigned)V + (unsigned)col;
        acc0[i][j][r] = logit + gumbel_at(gidx);
      }
    }
  // per-row argmax over this wave's 64 cols (within each 16-lane group).
  // sc == 1.0 exactly, so no denominator partials needed.
  const int grp = cn0 >> 6;   // 64 col-groups of 64
#pragma unroll
  for (int i = 0; i < 2; ++i) {
#pragma unroll
    for (int r = 0; r < 4; ++r) {
      float mx = -INFINITY; int ix = 0;
#pragma unroll
      for (int j = 0; j < 4; ++j) {
        const float w = acc0[i][j][r];
        const int col = cn0 + j * 16 + fr;
        if (w > mx) { mx = w; ix = col; }
      }
#pragma unroll
      for (int m = 1; m < 16; m <<= 1) {
        const float om = __shfl_xor(mx, m, 64);
        const int oi = __shfl_xor(ix, m, 64);
        if (om > mx || (om == mx && oi < ix)) { mx = om; ix = oi; }
      }
      if (fr == 0) {
        const int row = bm + wm + i * 16 + q4 + r;
        partM[(size_t)row * 64 + grp] = mx;
        partI[(size_t)row * 64 + grp] = ix;
      }
    }
  }
}

// ----------- finalize: argmax reduce, write one-hot, publish tok -----------
// (used once, after the loop, for the last emitted token)
__global__ __launch_bounds__(256) void finalize_kernel(
    const float* __restrict__ partM, const int* __restrict__ partI,
    float* __restrict__ out, int* __restrict__ tok,
    int step, int Tp1, int V)
{
  const int b = blockIdx.x;
  const int tid = threadIdx.x;
  __shared__ int s_tok;

  if (tid < 64) {
    float mx = partM[(size_t)b * 64 + tid];
    int ix = partI[(size_t)b * 64 + tid];
#pragma unroll
    for (int m = 1; m < 64; m <<= 1) {
      const float om = __shfl_xor(mx, m, 64);
      const int oi = __shfl_xor(ix, m, 64);
      if (om > mx || (om == mx && oi < ix)) { mx = om; ix = oi; }
    }
    if (tid == 0) { s_tok = ix; tok[b] = ix; }
  }
  __syncthreads();
  const int tk = s_tok;

  // one-hot write with exact 1.0 (sc == (1-y)+y == 1.0f identically)
  float* orow = out + ((size_t)b * Tp1 + step + 1) * V;
  const int tq = tk >> 2;
#pragma unroll
  for (int j = 0; j < 4; ++j) {
    const int idx = tid + 256 * j;
    float4 v = make_float4(0.f, 0.f, 0.f, 0.f);
    if (idx == tq) ((float*)&v)[tk & 3] = 1.0f;
    ((float4*)orow)[idx] = v;
  }
}

// ------------------------------- host side ---------------------------------

extern "C" void kernel_launch(void* const* d_in, const int* in_sizes, int n_in,
                              void* d_out, int out_size, void* d_ws, size_t ws_size,
                              hipStream_t stream) {
  const float* t     = (const float*)d_in[0];
  const float* emb   = (const float*)d_in[1];
  const float* affw  = (const float*)d_in[2];
  const float* affb  = (const float*)d_in[3];
  const float* wih   = (const float*)d_in[4];
  const float* whh   = (const float*)d_in[5];
  const float* bih   = (const float*)d_in[6];
  const float* bhh   = (const float*)d_in[7];
  const float* lpw   = (const float*)d_in[8];
  const float* lpb   = (const float*)d_in[9];
  const int*   start = (const int*)d_in[10];
  float* out = (float*)d_out;

  const int H = in_sizes[3];             // 1024
  const int V = in_sizes[9];             // 4096
  const int E = in_sizes[1] / V;         // 256
  const int F = in_sizes[2] / H;         // 2048
  const int B = in_sizes[0] / F;         // 1024
  const int Tp1 = out_size / (B * V);    // 33
  const int T = Tp1 - 1;                 // 32
  const int KG = E + H;                  // 1280
  const int NP = 4 * H;                  // 4096 packed gate cols (== V)

  // ---- workspace layout (~190 MB) ----
  char* p = (char*)d_ws;
  float* gihb  = (float*)p; p += (size_t)V * NP * 4;          // 64 MB gih table
  float* cbuf  = (float*)p; p += (size_t)B * H * 4;           // 4 MB
  f16* hA0[2]; f16* hA1[2];
  hA0[0] = (f16*)p; p += (size_t)B * H * 2;
  hA1[0] = (f16*)p; p += (size_t)B * H * 2;
  hA0[1] = (f16*)p; p += (size_t)B * H * 2;
  hA1[1] = (f16*)p; p += (size_t)B * H * 2;                   // 8 MB
  f16* wg0 = (f16*)p; p += (size_t)V * KG * 2;                // 21 MB packed gates
  f16* wg1 = (f16*)p; p += (size_t)V * KG * 2;
  f16* wl0 = (f16*)p; p += (size_t)V * H * 2;                 // 16 MB lp_w
  f16* wl1 = (f16*)p; p += (size_t)V * H * 2;
  f16* t0  = (f16*)p; p += (size_t)B * F * 2;                 // 8 MB t planes
  f16* t1  = (f16*)p; p += (size_t)B * F * 2;
  f16* aw0 = (f16*)p; p += (size_t)H * F * 2;                 // 8 MB aff_w planes
  f16* aw1 = (f16*)p; p += (size_t)H * F * 2;
  f16* em0 = (f16*)p; p += (size_t)V * E * 2;                 // 4 MB emb planes
  f16* em1 = (f16*)p; p += (size_t)V * E * 2;
  float* bgi = (float*)p; p += (size_t)NP * 4;
  float* bgh = (float*)p; p += (size_t)NP * 4;
  float* partM = (float*)p; p += (size_t)B * 64 * 4;
  int*   partI = (int*)p;   p += (size_t)B * 64 * 4;
  int*   tokb  = (int*)p;   p += (size_t)B * 4;
  (void)ws_size; (void)n_in;

  // ---- setup ----
  init_kernel<<<B, 256, 0, stream>>>(out, start, tokb, Tp1, V);
  pack_gates_kernel<<<dim3((KG + 255) / 256, NP), 256, 0, stream>>>(
      wih, whh, wg0, wg1, E, H, KG);
  pack_bias_kernel<<<NP / 256, 256, 0, stream>>>(bih, bhh, bgi, bgh, H);
  split_kernel<<<(V * H + 255) / 256, 256, 0, stream>>>(lpw, wl0, wl1, V * H);
  split_kernel<<<(B * F + 255) / 256, 256, 0, stream>>>(t, t0, t1, B * F);
  split_kernel<<<(H * F + 255) / 256, 256, 0, stream>>>(affw, aw0, aw1, H * F);
  split_kernel<<<(V * E + 255) / 256, 256, 0, stream>>>(emb, em0, em1, V * E);
  // h0 = t @ aff_w^T + aff_b -> split into hA[0]; zero cbuf
  h0_kernel<<<dim3(H / 128, B / 128), 512, 0, stream>>>(
      t0, t1, F, aw0, aw1, affb, hA0[0], hA1[0], H, cbuf);
  // gih = emb @ w_ih^T + b_ih + b_hh (packed cols), f32
  gih_kernel<<<dim3(NP / 128, V / 128), 512, 0, stream>>>(
      em0, em1, E, wg0, wg1, KG, bgi, bgh, gihb, NP);

  for (int s = 0; s < T; ++s) {
    const int cur = s & 1, nxt = (s + 1) & 1;
    gates_kernel<<<dim3(NP / 128, B / 128), 512, 0, stream>>>(
        hA0[cur], hA1[cur], H, wg0, wg1, KG, E, gihb, NP, tokb,
        partM, partI, out, s, Tp1, V,
        cbuf, hA0[nxt], hA1[nxt]);
    logits_kernel<<<dim3(V / 128, B / 128), 512, 0, stream>>>(
        hA0[nxt], hA1[nxt], H, wl0, wl1, lpb,
        partM, partI, s, B, V);
  }
  finalize_kernel<<<B, 256, 0, stream>>>(
      partM, partI, out, tokb, T - 1, Tp1, V);
}